// Round 1
// baseline (904.586 us; speedup 1.0000x reference)
//
#include <hip/hip_runtime.h>

// ---------------------------------------------------------------------------
// ConvLSTMNet: 7040 independent 64-unit LSTMs (2 subs x 2 cells x 32*55 seqs)
// x 256 steps, then a purely-linear FC chain 7040->3400->1000->500->50.
// Recurrent matmul done with mfma_f32_16x16x32_bf16, split-bf16 (hi+lo) for
// fp32-level accuracy. State update fp32 via v_exp/v_rcp.
// ---------------------------------------------------------------------------

#define T_STEPS 256
#define PIX 55
#define HCH 64
#define MT 16          // sequences per block (one MFMA M-tile)
#define TILES 110      // 1760 / 16

typedef float f32x4 __attribute__((ext_vector_type(4)));
typedef __bf16 bf16x8 __attribute__((ext_vector_type(8)));

__device__ __forceinline__ float fsig(float x) {
    // 1/(1+2^(-x*log2e))
    float e = __builtin_amdgcn_exp2f(-1.4426950408889634f * x);
    return __builtin_amdgcn_rcpf(1.0f + e);
}
__device__ __forceinline__ float ftanh(float x) {
    // 2/(1+2^(-2x*log2e)) - 1
    float e = __builtin_amdgcn_exp2f(-2.8853900817779268f * x);
    return 2.0f * __builtin_amdgcn_rcpf(1.0f + e) - 1.0f;
}

__global__ __launch_bounds__(256) void lstm_kernel(
    const float* __restrict__ x1, const float* __restrict__ x2,
    const float* __restrict__ wx1, const float* __restrict__ wh1,
    const float* __restrict__ bx1, const float* __restrict__ bh1,
    const float* __restrict__ wx2, const float* __restrict__ wh2,
    const float* __restrict__ bx2, const float* __restrict__ bh2,
    float* __restrict__ feat)   // (64 rows x 7040): row = sub*32+b, col = (cell*64+u)*55+p
{
    int bid  = blockIdx.x;            // 0..439
    int tile = bid % TILES;
    int cc   = bid / TILES;           // 0..3
    int sub  = cc >> 1, cell = cc & 1;
    const float* x  = sub  ? x2  : x1;
    const float* wx = cell ? wx2 : wx1;
    const float* wh = cell ? wh2 : wh1;
    const float* bx = cell ? bx2 : bx1;
    const float* bh = cell ? bh2 : bh1;

    int tid  = threadIdx.x;
    int w    = tid >> 6;              // wave id = gate id (i,f,o,g)
    int l    = tid & 63;
    int quad = l >> 4;
    int c16  = l & 15;

    __shared__ float xlds[MT * T_STEPS * 2];          // [m][t][c]  32 KB
    __shared__ float gbuf[4 * MT * 68];               // [gate][m][u pad68] 17.4 KB
    __shared__ __align__(16) __bf16 hbh[MT * 72];     // h hi, [m][u pad72]
    __shared__ __align__(16) __bf16 hbl[MT * 72];     // h lo

    // ---- stage x for this block's 16 sequences (all 256 steps) into LDS ----
    {
        int seq0 = tile * MT;
        for (int i = 0; i < 32; ++i) {
            int idx = tid + 256 * i;          // idx = m*512 + t*2 + c
            int m = idx >> 9;
            int t = (idx >> 1) & 255;
            int c = idx & 1;
            int seq = seq0 + m;
            int b = seq / PIX, p = seq % PIX;
            xlds[idx] = x[((b * T_STEPS + t) * 2 + c) * PIX + p];
        }
    }
    // ---- zero h buffers ----
    for (int i = tid; i < MT * 72; i += 256) { hbh[i] = (__bf16)0.0f; hbl[i] = (__bf16)0.0f; }

    // ---- register-resident wh B-fragments (hi+lo), bias, wx columns ----
    // B[k][n]: lane holds n = c16 (+16*t4 +64*w), k = 32*q + 8*quad + j
    bf16x8 Bhi[4][2], Blo[4][2];
    float btot[4], wx0v[4], wx1v[4];
#pragma unroll
    for (int t4 = 0; t4 < 4; ++t4) {
        int n = 64 * w + 16 * t4 + c16;
        btot[t4] = bx[n] + bh[n];
        wx0v[t4] = wx[n];
        wx1v[t4] = wx[256 + n];
#pragma unroll
        for (int q = 0; q < 2; ++q) {
#pragma unroll
            for (int j = 0; j < 8; ++j) {
                int k = 32 * q + 8 * quad + j;
                float wv = wh[k * 256 + n];
                __bf16 hi = (__bf16)wv;
                Bhi[t4][q][j] = hi;
                Blo[t4][q][j] = (__bf16)(wv - (float)hi);
            }
        }
    }

    // update-role mapping: this thread updates unit uu for m in {mb, mb+4, mb+8, mb+12}
    int uu = tid & 63;
    int mb = tid >> 6;
    float cst[4]  = {0.f, 0.f, 0.f, 0.f};
    float hfin[4] = {0.f, 0.f, 0.f, 0.f};

    __syncthreads();

    for (int t = 0; t < T_STEPS; ++t) {
        int tx = cell ? (T_STEPS - 1 - t) : t;   // cell2 runs time-reversed input

        // A fragments: A[m][k], m = c16, k = 32*q + 8*quad + j  (contiguous in hbuf row)
        bf16x8 Ah[2], Al[2];
#pragma unroll
        for (int q = 0; q < 2; ++q) {
            int off = c16 * 72 + 32 * q + 8 * quad;
            Ah[q] = *(const bf16x8*)&hbh[off];
            Al[q] = *(const bf16x8*)&hbl[off];
        }
        // x inputs for the 4 C-rows this lane owns (m = 4*quad + r)
        float xa[4], xb_[4];
#pragma unroll
        for (int r = 0; r < 4; ++r) {
            int m = 4 * quad + r;
            xa[r]  = xlds[m * 512 + tx * 2 + 0];
            xb_[r] = xlds[m * 512 + tx * 2 + 1];
        }

#pragma unroll
        for (int t4 = 0; t4 < 4; ++t4) {
            f32x4 acc;
#pragma unroll
            for (int r = 0; r < 4; ++r)
                acc[r] = btot[t4] + xa[r] * wx0v[t4] + xb_[r] * wx1v[t4];
            // split-bf16: hi*hi + lo*hi + hi*lo  (lo*lo negligible)
            acc = __builtin_amdgcn_mfma_f32_16x16x32_bf16(Ah[0], Bhi[t4][0], acc, 0, 0, 0);
            acc = __builtin_amdgcn_mfma_f32_16x16x32_bf16(Ah[1], Bhi[t4][1], acc, 0, 0, 0);
            acc = __builtin_amdgcn_mfma_f32_16x16x32_bf16(Al[0], Bhi[t4][0], acc, 0, 0, 0);
            acc = __builtin_amdgcn_mfma_f32_16x16x32_bf16(Al[1], Bhi[t4][1], acc, 0, 0, 0);
            acc = __builtin_amdgcn_mfma_f32_16x16x32_bf16(Ah[0], Blo[t4][0], acc, 0, 0, 0);
            acc = __builtin_amdgcn_mfma_f32_16x16x32_bf16(Ah[1], Blo[t4][1], acc, 0, 0, 0);
            // C layout: row m = 4*quad + r, col u = 16*t4 + c16 ; gate = w
#pragma unroll
            for (int r = 0; r < 4; ++r)
                gbuf[(w * MT + 4 * quad + r) * 68 + 16 * t4 + c16] = acc[r];
        }
        __syncthreads();

        // ---- state update: 4 units per thread ----
#pragma unroll
        for (int r = 0; r < 4; ++r) {
            int m = mb + 4 * r;
            float iv = gbuf[(0 * MT + m) * 68 + uu];
            float fv = gbuf[(1 * MT + m) * 68 + uu];
            float ov = gbuf[(2 * MT + m) * 68 + uu];
            float gv = gbuf[(3 * MT + m) * 68 + uu];
            float c_ = fsig(fv) * cst[r] + fsig(iv) * ftanh(gv);
            cst[r] = c_;
            float h = fsig(ov) * ftanh(c_);
            hfin[r] = h;
            __bf16 hi = (__bf16)h;
            hbh[m * 72 + uu] = hi;
            hbl[m * 72 + uu] = (__bf16)(h - (float)hi);
        }
        __syncthreads();
    }

    // ---- final feature write: feat[sub*32+b][(cell*64+u)*55+p] ----
#pragma unroll
    for (int r = 0; r < 4; ++r) {
        int m = mb + 4 * r;
        int seq = tile * MT + m;
        int b = seq / PIX, p = seq % PIX;
        feat[(sub * 32 + b) * 7040 + (cell * 64 + uu) * PIX + p] = hfin[r];
    }
}

// ---------------------------------------------------------------------------
// FC chain: out(64xN) = A(64xK) @ W(KxN) + bias. Split-K with fp32 atomics.
// ---------------------------------------------------------------------------
__global__ __launch_bounds__(256) void fc_init(float* __restrict__ out,
                                               const float* __restrict__ bias, int N) {
    int i = blockIdx.x * 256 + threadIdx.x;
    if (i < 64 * N) out[i] = bias[i % N];
}

__global__ __launch_bounds__(256) void fc_gemm(const float* __restrict__ A,
                                               const float* __restrict__ W,
                                               float* __restrict__ out,
                                               int K, int N, int kchunk) {
    __shared__ float al[32 * 68];     // A chunk transposed: [kc][m pad68]
    int tid = threadIdx.x;
    int nl  = tid & 63;
    int mg  = tid >> 6;               // 4 m-groups of 16 rows
    int n   = blockIdx.x * 64 + nl;
    int k0  = blockIdx.y * kchunk;
    int kend = min(K, k0 + kchunk);

    float acc[16];
#pragma unroll
    for (int j = 0; j < 16; ++j) acc[j] = 0.0f;

    for (int kb = k0; kb < kend; kb += 32) {
#pragma unroll
        for (int i = 0; i < 8; ++i) {
            int idx = tid + 256 * i;          // 0..2047
            int m  = idx >> 5;
            int kc = idx & 31;
            int k  = kb + kc;
            al[kc * 68 + m] = (k < kend) ? A[m * K + k] : 0.0f;
        }
        __syncthreads();
        int klim = min(32, kend - kb);
        for (int kc = 0; kc < klim; ++kc) {
            float wv = 0.0f;
            if (n < N) wv = W[(kb + kc) * N + n];
            const float4* a4 = (const float4*)&al[kc * 68 + mg * 16];
#pragma unroll
            for (int jj = 0; jj < 4; ++jj) {
                float4 av = a4[jj];
                acc[4 * jj + 0] += av.x * wv;
                acc[4 * jj + 1] += av.y * wv;
                acc[4 * jj + 2] += av.z * wv;
                acc[4 * jj + 3] += av.w * wv;
            }
        }
        __syncthreads();
    }
    if (n < N) {
#pragma unroll
        for (int j = 0; j < 16; ++j)
            atomicAdd(&out[(mg * 16 + j) * N + n], acc[j]);
    }
}

extern "C" void kernel_launch(void* const* d_in, const int* in_sizes, int n_in,
                              void* d_out, int out_size, void* d_ws, size_t ws_size,
                              hipStream_t stream) {
    const float* x1  = (const float*)d_in[0];
    const float* x2  = (const float*)d_in[1];
    const float* wx1 = (const float*)d_in[2];
    const float* wh1 = (const float*)d_in[3];
    const float* bx1 = (const float*)d_in[4];
    const float* bh1 = (const float*)d_in[5];
    const float* wx2 = (const float*)d_in[6];
    const float* wh2 = (const float*)d_in[7];
    const float* bx2 = (const float*)d_in[8];
    const float* bh2 = (const float*)d_in[9];
    const float* fw2 = (const float*)d_in[10];
    const float* fb2 = (const float*)d_in[11];
    const float* fw3 = (const float*)d_in[12];
    const float* fb3 = (const float*)d_in[13];
    const float* fw4 = (const float*)d_in[14];
    const float* fb4 = (const float*)d_in[15];
    const float* fw5 = (const float*)d_in[16];
    const float* fb5 = (const float*)d_in[17];

    char* ws = (char*)d_ws;
    float* feat = (float*)ws;                                        // 64*7040
    float* t1   = (float*)(ws + (size_t)64 * 7040 * 4);              // 64*3400
    float* t2   = (float*)(ws + (size_t)64 * (7040 + 3400) * 4);     // 64*1000
    float* t3   = (float*)(ws + (size_t)64 * (7040 + 3400 + 1000) * 4); // 64*500
    float* o    = (float*)d_out;                                     // 64*50 = out1(32x50)||out2(32x50)

    lstm_kernel<<<dim3(440), dim3(256), 0, stream>>>(
        x1, x2, wx1, wh1, bx1, bh1, wx2, wh2, bx2, bh2, feat);

    fc_init<<<dim3(850), dim3(256), 0, stream>>>(t1, fb2, 3400);
    fc_gemm<<<dim3(54, 8), dim3(256), 0, stream>>>(feat, fw2, t1, 7040, 3400, 880);

    fc_init<<<dim3(250), dim3(256), 0, stream>>>(t2, fb3, 1000);
    fc_gemm<<<dim3(16, 8), dim3(256), 0, stream>>>(t1, fw3, t2, 3400, 1000, 425);

    fc_init<<<dim3(125), dim3(256), 0, stream>>>(t3, fb4, 500);
    fc_gemm<<<dim3(8, 4), dim3(256), 0, stream>>>(t2, fw4, t3, 1000, 500, 250);

    fc_init<<<dim3(13), dim3(256), 0, stream>>>(o, fb5, 50);
    fc_gemm<<<dim3(1, 4), dim3(256), 0, stream>>>(t3, fw5, o, 500, 50, 125);
}

// Round 2
// 867.411 us; speedup vs baseline: 1.0429x; 1.0429x over previous
//
#include <hip/hip_runtime.h>

// ---------------------------------------------------------------------------
// ConvLSTMNet round 2:
//  - lstm: wave w owns units 16w..16w+15 for ALL 4 gates -> state update fully
//    in registers (no gbuf LDS round trip), double-buffered h, 1 barrier/step.
//  - FC: transposed activations [feature][64]; A = coalesced vector load,
//    W = wave-uniform s_loads, out = coalesced fp32 atomics. No LDS, no syncs.
// ---------------------------------------------------------------------------

#define T_STEPS 256
#define PIX 55
#define MT 16          // sequences per block (MFMA M-tile)
#define TILES 110      // 1760 / 16
#define LOG2E 1.4426950408889634f

typedef float f32x4 __attribute__((ext_vector_type(4)));
typedef __bf16 bf16x8 __attribute__((ext_vector_type(8)));

__global__ __launch_bounds__(256) void lstm_kernel(
    const float* __restrict__ x1, const float* __restrict__ x2,
    const float* __restrict__ wx1, const float* __restrict__ wh1,
    const float* __restrict__ bx1, const float* __restrict__ bh1,
    const float* __restrict__ wx2, const float* __restrict__ wh2,
    const float* __restrict__ bx2, const float* __restrict__ bh2,
    float* __restrict__ featT)   // [7040][64]: row f=(cell*64+u)*55+p, col sub*32+b
{
    int bid  = blockIdx.x;            // 0..439
    int tile = bid % TILES;
    int cc   = bid / TILES;           // 0..3
    int sub  = cc >> 1, cell = cc & 1;
    const float* x  = sub  ? x2  : x1;
    const float* wx = cell ? wx2 : wx1;
    const float* wh = cell ? wh2 : wh1;
    const float* bx = cell ? bx2 : bx1;
    const float* bh = cell ? bh2 : bh1;

    int tid  = threadIdx.x;
    int w    = tid >> 6;              // wave id = unit subtile (16 units)
    int l    = tid & 63;
    int quad = l >> 4;
    int c16  = l & 15;

    __shared__ float xl[MT * 514];                        // [m][t*2+c], stride 514 (pad)
    __shared__ __align__(16) __bf16 hb[2][2][MT][72];     // [buf][hi/lo][m][u pad72]

    // ---- stage x for this block's 16 sequences (all 256 steps) ----
    {
        int seq0 = tile * MT;
        for (int i = 0; i < 32; ++i) {
            int idx = tid + 256 * i;          // m*512 + t*2 + c
            int m = idx >> 9;
            int tc = idx & 511;
            int t = tc >> 1, c = tc & 1;
            int seq = seq0 + m;
            int b = seq / PIX, p = seq % PIX;
            xl[m * 514 + tc] = x[((b * T_STEPS + t) * 2 + c) * PIX + p];
        }
    }
    // ---- zero h buffer 0 (both hi and lo) ----
    {
        __bf16* hz = &hb[0][0][0][0];
        for (int i = tid; i < 2 * MT * 72; i += 256) hz[i] = (__bf16)0.0f;
    }

    // ---- register-resident wh B-fragments for 4 gates (hi+lo) ----
    // gate g -> columns n = 64*g + 16*w + c16 ; B[k][n], k = 32*q + 8*quad + j
    bf16x8 Bhi[4][2], Blo[4][2];
    float btot[4], wx0v[4], wx1v[4];
#pragma unroll
    for (int g = 0; g < 4; ++g) {
        int n = 64 * g + 16 * w + c16;
        btot[g] = bx[n] + bh[n];
        wx0v[g] = wx[n];
        wx1v[g] = wx[256 + n];
#pragma unroll
        for (int q = 0; q < 2; ++q) {
#pragma unroll
            for (int j = 0; j < 8; ++j) {
                int k = 32 * q + 8 * quad + j;
                float wv = wh[k * 256 + n];
                __bf16 hi = (__bf16)wv;
                Bhi[g][q][j] = hi;
                Blo[g][q][j] = (__bf16)(wv - (float)hi);
            }
        }
    }

    float cst[4]  = {0.f, 0.f, 0.f, 0.f};
    float hfin[4] = {0.f, 0.f, 0.f, 0.f};

    __syncthreads();

    for (int t = 0; t < T_STEPS; ++t) {
        int rb = t & 1, wb = rb ^ 1;
        int tx = cell ? (T_STEPS - 1 - t) : t;

        // A fragments from h buffer rb: A[m=c16][k = 32q + 8quad + j]
        bf16x8 Ah[2], Al[2];
#pragma unroll
        for (int q = 0; q < 2; ++q) {
            Ah[q] = *(const bf16x8*)&hb[rb][0][c16][32 * q + 8 * quad];
            Al[q] = *(const bf16x8*)&hb[rb][1][c16][32 * q + 8 * quad];
        }
        // x for the 4 C-rows this lane owns (m = 4*quad + r)
        float xa[4], xb_[4];
#pragma unroll
        for (int r = 0; r < 4; ++r) {
            float2 v = *(const float2*)&xl[(4 * quad + r) * 514 + tx * 2];
            xa[r] = v.x; xb_[r] = v.y;
        }

        f32x4 acc[4];
#pragma unroll
        for (int g = 0; g < 4; ++g) {
#pragma unroll
            for (int r = 0; r < 4; ++r)
                acc[g][r] = fmaf(xb_[r], wx1v[g], fmaf(xa[r], wx0v[g], btot[g]));
        }
#pragma unroll
        for (int g = 0; g < 4; ++g) {
            acc[g] = __builtin_amdgcn_mfma_f32_16x16x32_bf16(Ah[0], Bhi[g][0], acc[g], 0, 0, 0);
            acc[g] = __builtin_amdgcn_mfma_f32_16x16x32_bf16(Ah[1], Bhi[g][1], acc[g], 0, 0, 0);
            acc[g] = __builtin_amdgcn_mfma_f32_16x16x32_bf16(Al[0], Bhi[g][0], acc[g], 0, 0, 0);
            acc[g] = __builtin_amdgcn_mfma_f32_16x16x32_bf16(Al[1], Bhi[g][1], acc[g], 0, 0, 0);
            acc[g] = __builtin_amdgcn_mfma_f32_16x16x32_bf16(Ah[0], Blo[g][0], acc[g], 0, 0, 0);
            acc[g] = __builtin_amdgcn_mfma_f32_16x16x32_bf16(Ah[1], Blo[g][1], acc[g], 0, 0, 0);
        }

        // ---- state update fully in registers (i,f,o,g all in-lane) ----
#pragma unroll
        for (int r = 0; r < 4; ++r) {
            float iv = acc[0][r], fv = acc[1][r], ov = acc[2][r], gv = acc[3][r];
            float ei = __builtin_amdgcn_exp2f(-LOG2E * iv);
            float ef = __builtin_amdgcn_exp2f(-LOG2E * fv);
            float eo = __builtin_amdgcn_exp2f(-LOG2E * ov);
            float eg = __builtin_amdgcn_exp2f(-2.0f * LOG2E * gv);
            // sig(f)*c + sig(i)*tanh(g): sig(i)*tanh(g) = (1-eg)/((1+ei)(1+eg))
            float sf  = __builtin_amdgcn_rcpf(1.0f + ef);
            float itg = (1.0f - eg) * __builtin_amdgcn_rcpf((1.0f + ei) * (1.0f + eg));
            float c   = fmaf(sf, cst[r], itg);
            cst[r] = c;
            float ec = __builtin_amdgcn_exp2f(-2.0f * LOG2E * c);
            float h  = (1.0f - ec) * __builtin_amdgcn_rcpf((1.0f + eo) * (1.0f + ec));
            hfin[r] = h;
            int m = 4 * quad + r, u = 16 * w + c16;
            __bf16 hi = (__bf16)h;
            hb[wb][0][m][u] = hi;
            hb[wb][1][m][u] = (__bf16)(h - (float)hi);
        }
        __syncthreads();   // single barrier per step (h double-buffered)
    }

    // ---- final feature write (transposed layout) ----
#pragma unroll
    for (int r = 0; r < 4; ++r) {
        int m = 4 * quad + r;
        int seq = tile * MT + m;
        int b = seq / PIX, p = seq % PIX;
        int u = 16 * w + c16;
        featT[(size_t)((cell * 64 + u) * PIX + p) * 64 + sub * 32 + b] = hfin[r];
    }
}

// ---------------------------------------------------------------------------
// FC: out = A @ W + b.  AT is [K][64] (transposed activations).
// lane = m (coalesced A load + coalesced atomic); wave owns 16 n (uniform W
// row segment -> s_loads). Split-K over blockIdx.y with fp32 atomics.
// out layout: direct=0 -> [N][64] transposed; direct=1 -> [64][N] row-major.
// ---------------------------------------------------------------------------
__global__ __launch_bounds__(256) void fc_gemm(const float* __restrict__ AT,
                                               const float* __restrict__ W,
                                               const float* __restrict__ bias,
                                               float* __restrict__ out,
                                               int K, int N, int kchunk, int direct) {
    int tid = threadIdx.x;
    int l   = tid & 63;
    int wv  = __builtin_amdgcn_readfirstlane(tid >> 6);
    int n0  = blockIdx.x * 64 + wv * 16;
    int nlim = N - n0;
    if (nlim <= 0) return;                 // wave-uniform exit, no barriers used
    int k0   = blockIdx.y * kchunk;
    int kend = min(K, k0 + kchunk);

    float acc[16];
#pragma unroll
    for (int j = 0; j < 16; ++j) acc[j] = 0.0f;
    if (blockIdx.y == 0) {
#pragma unroll
        for (int j = 0; j < 16; ++j) if (j < nlim) acc[j] = bias[n0 + j];
    }

    if (nlim >= 16) {
#pragma unroll 2
        for (int k = k0; k < kend; ++k) {
            float a = AT[(size_t)k * 64 + l];                       // coalesced 256B
            int woff = __builtin_amdgcn_readfirstlane(k * N + n0);  // uniform -> s_load
#pragma unroll
            for (int j = 0; j < 16; ++j)
                acc[j] = fmaf(a, W[woff + j], acc[j]);
        }
    } else {
        for (int k = k0; k < kend; ++k) {
            float a = AT[(size_t)k * 64 + l];
            int woff = __builtin_amdgcn_readfirstlane(k * N + n0);
            for (int j = 0; j < nlim; ++j)
                acc[j] = fmaf(a, W[woff + j], acc[j]);
        }
    }

    if (direct) {
#pragma unroll
        for (int j = 0; j < 16; ++j) if (j < nlim)
            atomicAdd(&out[(size_t)l * N + (n0 + j)], acc[j]);
    } else {
#pragma unroll
        for (int j = 0; j < 16; ++j) if (j < nlim)
            atomicAdd(&out[(size_t)(n0 + j) * 64 + l], acc[j]);    // coalesced over l
    }
}

__global__ __launch_bounds__(256) void zero2(float* __restrict__ a, int na,
                                             float* __restrict__ b, int nb) {
    int i = blockIdx.x * 256 + threadIdx.x;
    if (i < na) a[i] = 0.0f;
    if (i < nb) b[i] = 0.0f;
}

extern "C" void kernel_launch(void* const* d_in, const int* in_sizes, int n_in,
                              void* d_out, int out_size, void* d_ws, size_t ws_size,
                              hipStream_t stream) {
    const float* x1  = (const float*)d_in[0];
    const float* x2  = (const float*)d_in[1];
    const float* wx1 = (const float*)d_in[2];
    const float* wh1 = (const float*)d_in[3];
    const float* bx1 = (const float*)d_in[4];
    const float* bh1 = (const float*)d_in[5];
    const float* wx2 = (const float*)d_in[6];
    const float* wh2 = (const float*)d_in[7];
    const float* bx2 = (const float*)d_in[8];
    const float* bh2 = (const float*)d_in[9];
    const float* fw2 = (const float*)d_in[10];
    const float* fb2 = (const float*)d_in[11];
    const float* fw3 = (const float*)d_in[12];
    const float* fb3 = (const float*)d_in[13];
    const float* fw4 = (const float*)d_in[14];
    const float* fb4 = (const float*)d_in[15];
    const float* fw5 = (const float*)d_in[16];
    const float* fb5 = (const float*)d_in[17];

    char* ws = (char*)d_ws;
    float* featT = (float*)ws;                                  // 7040*64
    float* t1T   = featT + (size_t)7040 * 64;                   // 3400*64
    float* t2T   = t1T   + (size_t)3400 * 64;                   // 1000*64
    float* t3T   = t2T   + (size_t)1000 * 64;                   //  500*64
    float* o     = (float*)d_out;                               // 64*50

    lstm_kernel<<<dim3(440), dim3(256), 0, stream>>>(
        x1, x2, wx1, wh1, bx1, bh1, wx2, wh2, bx2, bh2, featT);

    // zero t1T..t3T (contiguous: 4900*64 floats) and d_out, one launch
    zero2<<<dim3(1225), dim3(256), 0, stream>>>(t1T, 4900 * 64, o, 64 * 50);

    fc_gemm<<<dim3(54, 16), dim3(256), 0, stream>>>(featT, fw2, fb2, t1T, 7040, 3400, 440, 0);
    fc_gemm<<<dim3(16, 25), dim3(256), 0, stream>>>(t1T,  fw3, fb3, t2T, 3400, 1000, 136, 0);
    fc_gemm<<<dim3( 8, 25), dim3(256), 0, stream>>>(t2T,  fw4, fb4, t3T, 1000,  500,  40, 0);
    fc_gemm<<<dim3( 1, 25), dim3(256), 0, stream>>>(t3T,  fw5, fb5, o,    500,   50,  20, 1);
}